// Round 1
// baseline (155.280 us; speedup 1.0000x reference)
//
#include <hip/hip_runtime.h>
#include <math.h>

// Problem constants (fixed by setup_inputs)
#define BB   8
#define CH   64     // C_in = C_out
#define NN   4096
#define KK   16
#define CAT  128    // C_out + C_in
#define TILE 64     // nodes per block
#define NT   256

// ---------------------------------------------------------------------------
// Kernel A: preT[b][n][o] = relu( sum_c w_pre[o][c] * x[b][c][n] )
// Stored node-major so kernel B's neighbor gather reads contiguous 256B rows.
// Thread map: nl = t&63 (node within tile), og = t>>6 (o-quadrant, wave-uniform).
// ---------------------------------------------------------------------------
__global__ __launch_bounds__(NT) void pre_kernel(
    const float* __restrict__ x,      // [B][CH][NN]
    const float* __restrict__ w_pre,  // [CH][CH]
    float* __restrict__ preT)         // [B][NN][CH]
{
    __shared__ float outS[TILE][CH + 1];   // [n][o], pitch 65 -> conflict-free
    const int t  = threadIdx.x;
    const int nl = t & 63;
    const int og = __builtin_amdgcn_readfirstlane(t >> 6);  // wave-uniform
    const int m0 = blockIdx.x * TILE;
    const int b  = m0 / NN;
    const int n0 = m0 % NN;
    const int n  = n0 + nl;

    // x column for this node into registers (coalesced per c: lanes vary n)
    float xr[CH];
    const float* xb = x + (size_t)b * CH * NN + n;
#pragma unroll
    for (int c = 0; c < CH; ++c) xr[c] = xb[(size_t)c * NN];

    const float4* w4 = (const float4*)w_pre;  // [o][16 quads]
#pragma unroll 4
    for (int i = 0; i < 16; ++i) {
        const int o = og * 16 + i;
        float acc = 0.f;
#pragma unroll
        for (int c4 = 0; c4 < 16; ++c4) {     // wave-uniform address -> s_load
            const float4 w = w4[o * 16 + c4];
            acc += w.x * xr[c4 * 4 + 0];
            acc += w.y * xr[c4 * 4 + 1];
            acc += w.z * xr[c4 * 4 + 2];
            acc += w.w * xr[c4 * 4 + 3];
        }
        outS[nl][o] = fmaxf(acc, 0.f);        // stride-65 write, conflict-free
    }
    __syncthreads();

    // Coalesced write-out: lanes vary o (contiguous), rows split across groups
    const int o = nl;
#pragma unroll
    for (int j = 0; j < 16; ++j) {
        const int r = og * 16 + j;
        preT[((size_t)b * NN + n0 + r) * CH + o] = outS[r][o];
    }
}

// ---------------------------------------------------------------------------
// Kernel B: per node: aggr = max_k pre[:, idx_k]; cat=[x_col, aggr];
//           out = relu(w_nn @ cat) + bias; out /= max(||out||, 1e-12)
// ---------------------------------------------------------------------------
__global__ __launch_bounds__(NT) void main_kernel(
    const float* __restrict__ x,      // [B][CH][NN]
    const float* __restrict__ preT,   // [B][NN][CH]
    const float* __restrict__ w_nn,   // [CH][CAT]
    const float* __restrict__ bias,   // [CH]
    const int*   __restrict__ edge0,  // [B][NN][KK] (first half of edge_index)
    float* __restrict__ out)          // [B][CH][NN]
{
    __shared__ float catS[TILE][CAT + 5];  // pitch 133 (odd-ish stride)
    __shared__ float part[TILE][4];
    const int t    = threadIdx.x;
    const int lane = t & 63;
    const int wv   = __builtin_amdgcn_readfirstlane(t >> 6);  // wave-uniform
    const int m0   = blockIdx.x * TILE;
    const int b    = m0 / NN;
    const int n0   = m0 % NN;

    // Phase 1a: stage x rows: catS[node][c] = x[b][c][n0+node] (coalesced)
#pragma unroll
    for (int ci = 0; ci < 16; ++ci) {
        const int c = ci * 4 + wv;
        catS[lane][c] = x[((size_t)b * CH + c) * NN + n0 + lane];
    }

    // Phase 1b: gather-max. Wave-uniform neighbor row -> 256B coalesced loads.
    for (int i = 0; i < 16; ++i) {
        const int j = wv * 16 + i;
        const int n = n0 + j;
        int idxv = 0;
        if (lane < KK) idxv = edge0[((size_t)b * NN + n) * KK + lane];
        float aggr = -INFINITY;
#pragma unroll
        for (int k = 0; k < KK; ++k) {
            const int nb = __shfl(idxv, k, 64) & (NN - 1);  // mask = OOB insurance
            aggr = fmaxf(aggr, preT[((size_t)b * NN + nb) * CH + lane]);
        }
        catS[j][CH + lane] = aggr;
    }
    __syncthreads();

    // Phase 2: out[o] = sum_c w_nn[o][c] * cat[c]; 16 outputs per thread.
    float acc[16];
#pragma unroll
    for (int i = 0; i < 16; ++i) acc[i] = 0.f;
    const float4* w4 = (const float4*)w_nn;  // [o][32 quads]
#pragma unroll 8
    for (int c4 = 0; c4 < 32; ++c4) {
        const float4 cv = *(const float4*)&catS[lane][c4 * 4];
#pragma unroll
        for (int i = 0; i < 16; ++i) {       // wave-uniform w address
            const float4 w = w4[(wv * 16 + i) * 32 + c4];
            acc[i] += w.x * cv.x + w.y * cv.y + w.z * cv.z + w.w * cv.w;
        }
    }

    // Phase 3: relu + bias, cross-wave sum of squares, normalize.
    float o16[16];
    float ss = 0.f;
#pragma unroll
    for (int i = 0; i < 16; ++i) {
        const float v = fmaxf(acc[i], 0.f) + bias[wv * 16 + i];
        o16[i] = v;
        ss += v * v;
    }
    part[lane][wv] = ss;
    __syncthreads();  // also guarantees all catS reads of phase 2 are done
    const float s = part[lane][0] + part[lane][1] + part[lane][2] + part[lane][3];
    const float scale = 1.f / fmaxf(sqrtf(s), 1e-12f);
#pragma unroll
    for (int i = 0; i < 16; ++i)
        catS[lane][wv * 16 + i] = o16[i] * scale;  // reuse catS as out staging
    __syncthreads();

    // Phase 4: coalesced write out[b][o][n0+lane] (lanes vary n)
#pragma unroll
    for (int j = 0; j < 16; ++j) {
        const int o = wv * 16 + j;
        out[((size_t)b * CH + o) * NN + n0 + lane] = catS[lane][o];
    }
}

extern "C" void kernel_launch(void* const* d_in, const int* in_sizes, int n_in,
                              void* d_out, int out_size, void* d_ws, size_t ws_size,
                              hipStream_t stream) {
    const float* x     = (const float*)d_in[0];
    // d_in[1] = x_0 : unused by the reference
    const float* w_pre = (const float*)d_in[2];
    const float* w_nn  = (const float*)d_in[3];
    const float* bias  = (const float*)d_in[4];
    const int*   edge  = (const int*)d_in[5];   // [2][B][NN][KK]; slice 0 = first half

    float* preT = (float*)d_ws;                 // B*NN*CH floats = 8 MB
    float* outp = (float*)d_out;

    const dim3 grid(BB * NN / TILE);
    const dim3 block(NT);
    pre_kernel<<<grid, block, 0, stream>>>(x, w_pre, preT);
    main_kernel<<<grid, block, 0, stream>>>(x, preT, w_nn, bias, edge, outp);
}

// Round 2
// 108.187 us; speedup vs baseline: 1.4353x; 1.4353x over previous
//
#include <hip/hip_runtime.h>
#include <math.h>

// Problem constants (fixed by setup_inputs)
#define BB   8
#define CH   64     // C_in = C_out
#define NN   4096
#define KK   16
#define CAT  128    // C_out + C_in
#define TILE 64     // nodes per block
#define NT   1024   // 16 waves

// Block swizzle: physical blockIdx.x = tile*8 + b  ->  b = idx&7 keeps each
// batch's blocks on one XCD (round-robin heuristic) so its 1MB preT slice
// stays L2-resident during the gather.
__device__ inline void decode_block(int bi, int& b, int& n0) {
    b  = bi & 7;
    n0 = (bi >> 3) * TILE;
}

// ---------------------------------------------------------------------------
// Kernel A: preT[b][n][o] = relu( sum_c w_pre[o][c] * x[b][c][n] )
// node-major output so kernel B's neighbor gather reads contiguous 256B rows.
// 16 waves: wave wv computes outputs o = wv*4 .. wv*4+3 for node = lane.
// ---------------------------------------------------------------------------
__global__ __launch_bounds__(NT) void pre_kernel(
    const float* __restrict__ x,      // [B][CH][NN]
    const float* __restrict__ w_pre,  // [CH][CH]
    float* __restrict__ preT)         // [B][NN][CH]
{
    __shared__ float xS[TILE][68];    // node-major, pitch 68 (16B-aligned rows)
    __shared__ float oS[TILE][68];
    const int t    = threadIdx.x;
    const int lane = t & 63;
    const int wv   = __builtin_amdgcn_readfirstlane(t >> 6);  // 0..15, uniform
    int b, n0;
    decode_block(blockIdx.x, b, n0);

    // Stage x tile: xS[node][c] = x[b][c][n0+node]; lanes vary node -> 256B
#pragma unroll
    for (int p = 0; p < 4; ++p) {
        const int c = wv + 16 * p;    // wave-uniform channel
        xS[lane][c] = x[((size_t)b * CH + c) * NN + n0 + lane];
    }
    __syncthreads();

    float acc[4] = {0.f, 0.f, 0.f, 0.f};
    const float4* w4 = (const float4*)w_pre;  // [o][16 quads]
#pragma unroll
    for (int c4 = 0; c4 < 16; ++c4) {
        const float4 cv = *(const float4*)&xS[lane][c4 * 4];
#pragma unroll
        for (int i = 0; i < 4; ++i) {         // wave-uniform w address -> s_load
            const float4 w = w4[(wv * 4 + i) * 16 + c4];
            acc[i] += w.x * cv.x + w.y * cv.y + w.z * cv.z + w.w * cv.w;
        }
    }
#pragma unroll
    for (int i = 0; i < 4; ++i) oS[lane][wv * 4 + i] = fmaxf(acc[i], 0.f);
    __syncthreads();

    // Write-out: lanes vary o (contiguous 256B), rows split across waves
#pragma unroll
    for (int p = 0; p < 4; ++p) {
        const int r = wv + 16 * p;
        preT[((size_t)b * NN + n0 + r) * CH + lane] = oS[r][lane];
    }
}

// ---------------------------------------------------------------------------
// Kernel B: per node: aggr = max_k preT[idx_k]; cat=[x_col, aggr];
//           out = relu(w_nn @ cat) + bias; out /= max(||out||, 1e-12)
// 16 waves: wave wv gathers nodes wv*4..wv*4+3 and computes o = wv*4..wv*4+3.
// ---------------------------------------------------------------------------
__global__ __launch_bounds__(NT) void main_kernel(
    const float* __restrict__ x,      // [B][CH][NN]
    const float* __restrict__ preT,   // [B][NN][CH]
    const float* __restrict__ w_nn,   // [CH][CAT]
    const float* __restrict__ bias,   // [CH]
    const int*   __restrict__ edge0,  // [B][NN][KK]
    float* __restrict__ out)          // [B][CH][NN]
{
    __shared__ float catS[TILE][CAT + 4];   // pitch 132 (16B-aligned rows)
    __shared__ float part[TILE][17];
    const int t    = threadIdx.x;
    const int lane = t & 63;
    const int wv   = __builtin_amdgcn_readfirstlane(t >> 6);  // 0..15, uniform
    int b, n0;
    decode_block(blockIdx.x, b, n0);

    // Phase 1a: stage x columns: catS[node][c] = x[b][c][n0+node]
#pragma unroll
    for (int p = 0; p < 4; ++p) {
        const int c = wv + 16 * p;
        catS[lane][c] = x[((size_t)b * CH + c) * NN + n0 + lane];
    }

    // Phase 1b: gather-max. Wave wv owns nodes wv*4..+3; one coalesced idx
    // load covers all 4 rows (64 ints). Neighbor rows are contiguous 256B.
    const int idxv = edge0[((size_t)b * NN + n0 + wv * 4) * KK + lane];
    float ag[4];
#pragma unroll
    for (int i = 0; i < 4; ++i) ag[i] = -INFINITY;
#pragma unroll
    for (int i = 0; i < 4; ++i) {
#pragma unroll
        for (int k = 0; k < KK; ++k) {
            const int nb = __shfl(idxv, i * KK + k, 64) & (NN - 1);
            ag[i] = fmaxf(ag[i], preT[((size_t)b * NN + nb) * CH + lane]);
        }
    }
#pragma unroll
    for (int i = 0; i < 4; ++i) catS[wv * 4 + i][CH + lane] = ag[i];
    __syncthreads();

    // Phase 2: out[o] = sum_c w_nn[o][c]*cat[c]; 4 outputs/thread, node=lane.
    float acc[4] = {0.f, 0.f, 0.f, 0.f};
    const float4* w4 = (const float4*)w_nn;   // [o][32 quads]
#pragma unroll
    for (int c4 = 0; c4 < 32; ++c4) {
        const float4 cv = *(const float4*)&catS[lane][c4 * 4];
#pragma unroll
        for (int i = 0; i < 4; ++i) {         // wave-uniform w address -> s_load
            const float4 w = w4[(wv * 4 + i) * 32 + c4];
            acc[i] += w.x * cv.x + w.y * cv.y + w.z * cv.z + w.w * cv.w;
        }
    }

    // Phase 3: relu + bias, cross-wave sum-of-squares per node, normalize.
    float o4[4];
    float ss = 0.f;
#pragma unroll
    for (int i = 0; i < 4; ++i) {
        const float v = fmaxf(acc[i], 0.f) + bias[wv * 4 + i];
        o4[i] = v;
        ss += v * v;
    }
    part[lane][wv] = ss;
    __syncthreads();
    float s = 0.f;
#pragma unroll
    for (int w = 0; w < 16; ++w) s += part[lane][w];
    const float scale = 1.f / fmaxf(sqrtf(s), 1e-12f);

    // Phase 4: direct coalesced write: lanes vary n for each o row.
#pragma unroll
    for (int i = 0; i < 4; ++i)
        out[((size_t)b * CH + wv * 4 + i) * NN + n0 + lane] = o4[i] * scale;
}

extern "C" void kernel_launch(void* const* d_in, const int* in_sizes, int n_in,
                              void* d_out, int out_size, void* d_ws, size_t ws_size,
                              hipStream_t stream) {
    const float* x     = (const float*)d_in[0];
    // d_in[1] = x_0 : unused by the reference
    const float* w_pre = (const float*)d_in[2];
    const float* w_nn  = (const float*)d_in[3];
    const float* bias  = (const float*)d_in[4];
    const int*   edge  = (const int*)d_in[5];   // [2][B][NN][KK]; slice 0

    float* preT = (float*)d_ws;                 // B*NN*CH floats = 8 MB
    float* outp = (float*)d_out;

    const dim3 grid(BB * NN / TILE);            // 512 blocks (swizzled decode)
    const dim3 block(NT);
    pre_kernel<<<grid, block, 0, stream>>>(x, w_pre, preT);
    main_kernel<<<grid, block, 0, stream>>>(x, preT, w_nn, bias, edge, outp);
}

// Round 3
// 88.296 us; speedup vs baseline: 1.7586x; 1.2253x over previous
//
#include <hip/hip_runtime.h>
#include <math.h>

// Problem constants (fixed by setup_inputs)
#define BB   8
#define CH   64     // C_in = C_out
#define NN   4096
#define KK   16
#define TILE 64     // nodes per block
#define NT   1024   // 16 waves
#define PP   72     // LDS pitch (bf16 elems) for 64-wide rows: 144 B, 16B-aligned
#define CP   136    // LDS pitch (bf16 elems) for 128-wide rows: 272 B, 16B-aligned

typedef __attribute__((ext_vector_type(8))) short bf16x8;  // 8 bf16 = 4 VGPR
typedef __attribute__((ext_vector_type(4))) float f32x4;

__device__ inline unsigned f2bf(float f) {   // RNE f32 -> bf16 bits
    union { float f; unsigned u; } v; v.f = f;
    return (v.u + 0x7FFFu + ((v.u >> 16) & 1u)) >> 16;
}

// Swizzle: b = idx&7 keeps each batch's blocks on one XCD (L2 locality).
__device__ inline void decode_block(int bi, int& b, int& n0) {
    b = bi & 7; n0 = (bi >> 3) * TILE;
}

// ---------------------------------------------------------------------------
// Kernel A: preB[b][n][o] = bf16( relu( w_pre @ x[b][:,n] ) ), node-major.
// MFMA 16x16x32 bf16: wave wv -> M-tile (wv&3: 16 out ch), N-tile (wv>>2: 16 nodes).
// ---------------------------------------------------------------------------
__global__ __launch_bounds__(NT, 8) void pre_kernel(
    const float* __restrict__ x,      // [B][CH][NN] f32
    const float* __restrict__ w_pre,  // [CH][CH] f32
    unsigned short* __restrict__ preB)// [B][NN][CH] bf16
{
    __shared__ unsigned short xT[TILE * PP];  // [node][c]
    __shared__ unsigned short wS[CH * PP];    // [o][c]
    const int t    = threadIdx.x;
    const int lane = t & 63;
    const int wv   = __builtin_amdgcn_readfirstlane(t >> 6);
    int b, n0; decode_block(blockIdx.x, b, n0);

    // Stage x tile as bf16: 4 consecutive channels/thread -> one ds_write_b64
    {
        const int c0 = wv * 4;
        unsigned h[4];
#pragma unroll
        for (int p = 0; p < 4; ++p)
            h[p] = f2bf(x[((size_t)b * CH + c0 + p) * NN + n0 + lane]);
        uint2 pk; pk.x = h[0] | (h[1] << 16); pk.y = h[2] | (h[3] << 16);
        *(uint2*)&xT[lane * PP + c0] = pk;
    }
    // Stage w_pre as bf16: thread t -> row o=t>>4, cols (t&15)*4..+3
    {
        const int o = t >> 4, c0 = (t & 15) * 4;
        const float4 w = *(const float4*)&w_pre[o * CH + c0];
        uint2 pk; pk.x = f2bf(w.x) | (f2bf(w.y) << 16);
        pk.y = f2bf(w.z) | (f2bf(w.w) << 16);
        *(uint2*)&wS[o * PP + c0] = pk;
    }
    __syncthreads();

    const int mt = wv & 3, nt = wv >> 2, nl = lane & 15, q = lane >> 4;
    // A-frag: A[m=nl][k=q*8+j]; B-frag: B[k=q*8+j][n=nl]  (K=64 -> 2 steps)
    const bf16x8 a0 = *(const bf16x8*)&wS[(mt * 16 + nl) * PP + q * 8];
    const bf16x8 a1 = *(const bf16x8*)&wS[(mt * 16 + nl) * PP + 32 + q * 8];
    const bf16x8 b0 = *(const bf16x8*)&xT[(nt * 16 + nl) * PP + q * 8];
    const bf16x8 b1 = *(const bf16x8*)&xT[(nt * 16 + nl) * PP + 32 + q * 8];
    f32x4 acc = {0.f, 0.f, 0.f, 0.f};
    acc = __builtin_amdgcn_mfma_f32_16x16x32_bf16(a0, b0, acc, 0, 0, 0);
    acc = __builtin_amdgcn_mfma_f32_16x16x32_bf16(a1, b1, acc, 0, 0, 0);

    // D: col=nl (node), row=q*4+r (out ch). 4 consecutive o -> 8B store.
    const int n = n0 + nt * 16 + nl;
    unsigned h0 = f2bf(fmaxf(acc[0], 0.f)), h1 = f2bf(fmaxf(acc[1], 0.f));
    unsigned h2 = f2bf(fmaxf(acc[2], 0.f)), h3 = f2bf(fmaxf(acc[3], 0.f));
    uint2 pk; pk.x = h0 | (h1 << 16); pk.y = h2 | (h3 << 16);
    *(uint2*)&preB[((size_t)b * NN + n) * CH + mt * 16 + q * 4] = pk;
}

// ---------------------------------------------------------------------------
// Kernel B: aggr = max_k preB[idx_k] (bf16 umax, relu>=0 so bits order);
//           cat=[x, aggr] bf16; out = relu(w_nn @ cat)+bias; L2-normalize.
// ---------------------------------------------------------------------------
__global__ __launch_bounds__(NT, 8) void main_kernel(
    const float* __restrict__ x,            // [B][CH][NN] f32
    const unsigned short* __restrict__ preB,// [B][NN][CH] bf16
    const float* __restrict__ w_nn,         // [CH][2*CH] f32
    const float* __restrict__ bias,         // [CH] f32
    const int* __restrict__ edge0,          // [B][NN][KK] int32
    float* __restrict__ out)                // [B][CH][NN] f32
{
    __shared__ unsigned short catT[TILE * CP];  // [node][c], c<64 = x, c>=64 = aggr
    __shared__ unsigned short wS[CH * CP];      // [o][c]
    __shared__ float part[TILE][4];
    const int t    = threadIdx.x;
    const int lane = t & 63;
    const int wv   = __builtin_amdgcn_readfirstlane(t >> 6);
    int b, n0; decode_block(blockIdx.x, b, n0);

    // idx early (latency): one coalesced load covers this wave's 4 nodes
    const int idxv = edge0[((size_t)b * NN + n0 + wv * 4) * KK + lane];

    // Stage w_nn as bf16: thread t -> row o=t>>4, cols (t&15)*8..+7 (b128)
    {
        const int o = t >> 4, c0 = (t & 15) * 8;
        const float4 wa = *(const float4*)&w_nn[o * 2 * CH + c0];
        const float4 wb = *(const float4*)&w_nn[o * 2 * CH + c0 + 4];
        uint4 pk;
        pk.x = f2bf(wa.x) | (f2bf(wa.y) << 16);
        pk.y = f2bf(wa.z) | (f2bf(wa.w) << 16);
        pk.z = f2bf(wb.x) | (f2bf(wb.y) << 16);
        pk.w = f2bf(wb.z) | (f2bf(wb.w) << 16);
        *(uint4*)&wS[o * CP + c0] = pk;
    }
    // Stage x tile as bf16 into catT[node][0..63]
    {
        const int c0 = wv * 4;
        unsigned h[4];
#pragma unroll
        for (int p = 0; p < 4; ++p)
            h[p] = f2bf(x[((size_t)b * CH + c0 + p) * NN + n0 + lane]);
        uint2 pk; pk.x = h[0] | (h[1] << 16); pk.y = h[2] | (h[3] << 16);
        *(uint2*)&catT[lane * CP + c0] = pk;
    }
    // Gather-max: wave wv owns nodes wv*4..+3; lane = channel; rows 128B.
    // relu output >= 0 -> bf16 bits are monotone -> unsigned max, no cvt.
    const unsigned short* pb = preB + (size_t)b * NN * CH + lane;
#pragma unroll
    for (int i = 0; i < 4; ++i) {
        unsigned ag = 0;
#pragma unroll
        for (int k = 0; k < KK; ++k) {
            const int nb = __shfl(idxv, i * KK + k, 64) & (NN - 1);
            const unsigned v = pb[(size_t)nb * CH];
            ag = ag > v ? ag : v;
        }
        catT[(wv * 4 + i) * CP + CH + lane] = (unsigned short)ag;
    }
    __syncthreads();

    // MFMA: wave wv -> M-tile mt (16 out ch), N-tile nt (16 nodes); K=128.
    const int mt = wv & 3, nt = wv >> 2, nl = lane & 15, q = lane >> 4;
    f32x4 acc = {0.f, 0.f, 0.f, 0.f};
#pragma unroll
    for (int kq = 0; kq < 4; ++kq) {
        const bf16x8 af = *(const bf16x8*)&wS[(mt * 16 + nl) * CP + kq * 32 + q * 8];
        const bf16x8 bf = *(const bf16x8*)&catT[(nt * 16 + nl) * CP + kq * 32 + q * 8];
        acc = __builtin_amdgcn_mfma_f32_16x16x32_bf16(af, bf, acc, 0, 0, 0);
    }

    // Epilogue: relu+bias, sum-of-squares over 64 ch (quads + m-tiles), norm.
    float v[4], ss = 0.f;
#pragma unroll
    for (int r = 0; r < 4; ++r) {
        v[r] = fmaxf(acc[r], 0.f) + bias[mt * 16 + q * 4 + r];
        ss += v[r] * v[r];
    }
    ss += __shfl_xor(ss, 16, 64);   // reduce across quads (rows within m-tile)
    ss += __shfl_xor(ss, 32, 64);
    if (lane < 16) part[nt * 16 + nl][mt] = ss;
    __syncthreads();
    const float s4 = part[nt * 16 + nl][0] + part[nt * 16 + nl][1]
                   + part[nt * 16 + nl][2] + part[nt * 16 + nl][3];
    const float scale = 1.f / fmaxf(sqrtf(s4), 1e-12f);

    // Store: per reg r, lanes of a quad cover 16 consecutive n (64B segments)
    const int n = n0 + nt * 16 + nl;
#pragma unroll
    for (int r = 0; r < 4; ++r)
        out[((size_t)b * CH + mt * 16 + q * 4 + r) * NN + n] = v[r] * scale;
}

extern "C" void kernel_launch(void* const* d_in, const int* in_sizes, int n_in,
                              void* d_out, int out_size, void* d_ws, size_t ws_size,
                              hipStream_t stream) {
    const float* x     = (const float*)d_in[0];
    // d_in[1] = x_0 : unused by the reference
    const float* w_pre = (const float*)d_in[2];
    const float* w_nn  = (const float*)d_in[3];
    const float* bias  = (const float*)d_in[4];
    const int*   edge  = (const int*)d_in[5];   // [2][B][NN][KK]; slice 0

    unsigned short* preB = (unsigned short*)d_ws;  // B*NN*CH bf16 = 4 MB
    float* outp = (float*)d_out;

    const dim3 grid(BB * NN / TILE);   // 512 blocks
    const dim3 block(NT);
    pre_kernel<<<grid, block, 0, stream>>>(x, w_pre, preB);
    main_kernel<<<grid, block, 0, stream>>>(x, preB, w_nn, bias, edge, outp);
}